// Round 1
// baseline (279.262 us; speedup 1.0000x reference)
//
#include <hip/hip_runtime.h>

// Problem constants (fixed by setup_inputs)
constexpr int Bc = 2, Dc = 48, Hc = 512, Wc = 640;
constexpr int HWc = Hc * Wc;

// Tile: 32x16 spatial, 256 threads, 2 consecutive-w pixels per thread.
// All 48 d-planes per block (DSPLIT=1) -> offset tensor fetched ONCE.
constexpr int TW = 32, TH = 16, NT = 256;
constexpr int HALO = 4;                       // far taps reach +/-4
constexpr int SW = TW + 2 * HALO;             // 40 (10 float4 per row)
constexpr int SH = TH + 2 * HALO;             // 24
constexpr int PLANE = SW * SH;                // 960 floats/plane
constexpr int DC = 2;                         // d-planes per barrier interval
constexpr int NIT = Dc / DC;                  // 24 intervals
constexpr int NVEC = DC * PLANE / 4;          // 480 float4 per interval
constexpr int VPT = (NVEC + NT - 1) / NT;     // 2
constexpr int NSC = DC * PLANE;               // 1920 scalars per interval
constexpr int SPT = (NSC + NT - 1) / NT;      // 8

__device__ __forceinline__ int reflect_h(int h) {
    return h < 0 ? -h : (h >= Hc ? 2 * (Hc - 1) - h : h);
}
__device__ __forceinline__ int reflect_w(int w) {
    return w < 0 ? -w : (w >= Wc ? 2 * (Wc - 1) - w : w);
}

// LDS = 15.36 KB -> LDS allows 10 blocks/CU; VGPR (~76) allows 6 -> 24 waves/CU.
__global__ __launch_bounds__(NT) void dw_kernel(
    const float* __restrict__ ds, const float* __restrict__ dmin,
    const float* __restrict__ dmax, const float* __restrict__ off,
    const float* __restrict__ scale_p, float* __restrict__ out)
{
    __shared__ float sx[2][DC * PLANE];       // double-buffered (15360 B)

    const int b   = blockIdx.z;
    const int h0  = blockIdx.y * TH;
    const int w0  = blockIdx.x * TW;
    const int tid = threadIdx.x;
    const int col = tid & 15;                 // 16 float2-groups across 32 w
    const int row = tid >> 4;                 // 0..15

    const float inv_min   = 1.0f / dmin[b];
    const float inv_max   = 1.0f / dmax[b];
    const float invd      = 1.0f / (inv_min - inv_max);
    const float inv_scale = 1.0f / scale_p[0];

    // 18 offset channels x 2 pixels -> 36 registers (float2 loads), reused 48x.
    float offF[9][2], offN[9][2];
    {
        const float* op = off + (size_t)b * 18 * HWc
                        + (size_t)(h0 + row) * Wc + (w0 + 2 * col);
        #pragma unroll
        for (int s = 0; s < 9; ++s) {
            float2 vF = *(const float2*)(op + (size_t)s * HWc);
            float2 vN = *(const float2*)(op + (size_t)(s + 9) * HWc);
            offF[s][0] = vF.x; offF[s][1] = vF.y;
            offN[s][0] = vN.x; offN[s][1] = vN.y;
        }
    }

    const float* dsb  = ds  + (size_t)b * Dc * HWc;
    float*       outb = out + (size_t)b * Dc * HWc
                            + (size_t)(h0 + row) * Wc + (w0 + 2 * col);

    // Stencil for one interval. Per plane: 17 ds_read_b64 feed 2 pixels.
    auto compute = [&](const float* sb, int d0) {
        #pragma unroll
        for (int p = 0; p < DC; ++p) {
            // bp -> this thread's center pixel (even word offset: b64 aligned)
            const float* bp = sb + p * PLANE + (row + HALO) * SW + (HALO + 2 * col);
            float a0 = 0.f, a1 = 0.f, x00, x01;
            float2 t0, t1, t2, t3, t4;
            // dy=-4: far row sy=0 (taps at w-4, w, w+4)
            t0 = *(const float2*)(bp - 4 * SW - 4);
            t1 = *(const float2*)(bp - 4 * SW);
            t2 = *(const float2*)(bp - 4 * SW + 4);
            a0 += offF[0][0]*t0.x + offF[1][0]*t1.x + offF[2][0]*t2.x;
            a1 += offF[0][1]*t0.y + offF[1][1]*t1.y + offF[2][1]*t2.y;
            // dy=-2: near row sy=0 (taps at w-2, w, w+2)
            t0 = *(const float2*)(bp - 2 * SW - 2);
            t1 = *(const float2*)(bp - 2 * SW);
            t2 = *(const float2*)(bp - 2 * SW + 2);
            a0 += offN[0][0]*t0.x + offN[1][0]*t1.x + offN[2][0]*t2.x;
            a1 += offN[0][1]*t0.y + offN[1][1]*t1.y + offN[2][1]*t2.y;
            // dy=0: near+far sy=1, center
            t0 = *(const float2*)(bp - 4);
            t1 = *(const float2*)(bp - 2);
            t2 = *(const float2*)(bp);
            t3 = *(const float2*)(bp + 2);
            t4 = *(const float2*)(bp + 4);
            x00 = t2.x; x01 = t2.y;
            a0 += offN[3][0]*t1.x + offN[4][0]*t2.x + offN[5][0]*t3.x
                + offF[3][0]*t0.x + offF[4][0]*t2.x + offF[5][0]*t4.x;
            a1 += offN[3][1]*t1.y + offN[4][1]*t2.y + offN[5][1]*t3.y
                + offF[3][1]*t0.y + offF[4][1]*t2.y + offF[5][1]*t4.y;
            // dy=+2: near row sy=2
            t0 = *(const float2*)(bp + 2 * SW - 2);
            t1 = *(const float2*)(bp + 2 * SW);
            t2 = *(const float2*)(bp + 2 * SW + 2);
            a0 += offN[6][0]*t0.x + offN[7][0]*t1.x + offN[8][0]*t2.x;
            a1 += offN[6][1]*t0.y + offN[7][1]*t1.y + offN[8][1]*t2.y;
            // dy=+4: far row sy=2
            t0 = *(const float2*)(bp + 4 * SW - 4);
            t1 = *(const float2*)(bp + 4 * SW);
            t2 = *(const float2*)(bp + 4 * SW + 4);
            a0 += offF[6][0]*t0.x + offF[7][0]*t1.x + offF[8][0]*t2.x;
            a1 += offF[6][1]*t0.y + offF[7][1]*t1.y + offF[8][1]*t2.y;
            // epilogue
            float2 o;
            a0 *= 0.5f; a1 *= 0.5f;
            float x1a = fminf(fabsf(a0 - x00) * inv_scale, 4.0f);
            float x1b = fminf(fabsf(a1 - x01) * inv_scale, 4.0f);
            o.x = __builtin_amdgcn_rcpf(1.0f + __expf(-(4.0f - 2.0f * x1a)));
            o.y = __builtin_amdgcn_rcpf(1.0f + __expf(-(4.0f - 2.0f * x1b)));
            *(float2*)(outb + (size_t)(d0 + p) * HWc) = o;
        }
    };

    // w-reflect only touches first/last block column; others vectorize.
    const bool interior = (blockIdx.x > 0) && (blockIdx.x + 1 < gridDim.x);

    if (interior) {
        int vsrc[VPT];                        // d-invariant source offsets
        #pragma unroll
        for (int i = 0; i < VPT; ++i) {
            int vid = tid + i * NT;
            if (vid < NVEC) {
                int p   = vid / (PLANE / 4);
                int rem = vid - p * (PLANE / 4);
                int r   = rem / (SW / 4);
                int j   = rem - r * (SW / 4);
                int hs  = reflect_h(h0 + r - HALO);
                vsrc[i] = p * HWc + hs * Wc + (w0 - HALO + 4 * j);
            } else vsrc[i] = 0;
        }
        float4 pre[VPT];
        auto issue = [&](int d0) {            // loads only -> in flight under compute
            const float* dp = dsb + (size_t)d0 * HWc;
            #pragma unroll
            for (int i = 0; i < VPT; ++i) {
                int vid = tid + i * NT;
                if (vid < NVEC) pre[i] = *(const float4*)(dp + vsrc[i]);
            }
        };
        auto commit = [&](float* sb) {
            #pragma unroll
            for (int i = 0; i < VPT; ++i) {
                int vid = tid + i * NT;
                if (vid < NVEC) {
                    float4 v = pre[i], x;
                    x.x = (__builtin_amdgcn_rcpf(v.x) - inv_max) * invd;
                    x.y = (__builtin_amdgcn_rcpf(v.y) - inv_max) * invd;
                    x.z = (__builtin_amdgcn_rcpf(v.z) - inv_max) * invd;
                    x.w = (__builtin_amdgcn_rcpf(v.w) - inv_max) * invd;
                    *(float4*)(sb + vid * 4) = x;
                }
            }
        };
        issue(0);
        commit(sx[0]);
        __syncthreads();
        for (int it = 0; it < NIT; ++it) {
            if (it + 1 < NIT) issue((it + 1) * DC);
            compute(sx[it & 1], it * DC);
            if (it + 1 < NIT) commit(sx[(it + 1) & 1]);
            __syncthreads();
        }
    } else {
        int ssrc[SPT];                        // scalar path (w-edge blocks)
        #pragma unroll
        for (int i = 0; i < SPT; ++i) {
            int idx = tid + i * NT;
            if (idx < NSC) {
                int p   = idx / PLANE;
                int rem = idx - p * PLANE;
                int r   = rem / SW;
                int c   = rem - r * SW;
                int hs  = reflect_h(h0 + r - HALO);
                int ws  = reflect_w(w0 + c - HALO);
                ssrc[i] = p * HWc + hs * Wc + ws;
            } else ssrc[i] = 0;
        }
        float pre[SPT];
        auto issue = [&](int d0) {
            const float* dp = dsb + (size_t)d0 * HWc;
            #pragma unroll
            for (int i = 0; i < SPT; ++i) {
                int idx = tid + i * NT;
                if (idx < NSC) pre[i] = dp[ssrc[i]];
            }
        };
        auto commit = [&](float* sb) {
            #pragma unroll
            for (int i = 0; i < SPT; ++i) {
                int idx = tid + i * NT;
                if (idx < NSC)
                    sb[idx] = (__builtin_amdgcn_rcpf(pre[i]) - inv_max) * invd;
            }
        };
        issue(0);
        commit(sx[0]);
        __syncthreads();
        for (int it = 0; it < NIT; ++it) {
            if (it + 1 < NIT) issue((it + 1) * DC);
            compute(sx[it & 1], it * DC);
            if (it + 1 < NIT) commit(sx[(it + 1) & 1]);
            __syncthreads();
        }
    }
}

extern "C" void kernel_launch(void* const* d_in, const int* in_sizes, int n_in,
                              void* d_out, int out_size, void* d_ws, size_t ws_size,
                              hipStream_t stream) {
    const float* ds   = (const float*)d_in[0];  // depth_sample [B,D,H,W]
    const float* dmin = (const float*)d_in[1];  // depth_min [B]
    const float* dmax = (const float*)d_in[2];  // depth_max [B]
    const float* off  = (const float*)d_in[3];  // offset [B,18,H,W]
    const float* sc   = (const float*)d_in[4];  // patchmatch_interval_scale
    float* out = (float*)d_out;                 // [B,D,H,W] fp32

    dim3 grid(Wc / TW, Hc / TH, Bc);            // (20, 32, 2) = 1280 blocks = 5.0/CU
    dw_kernel<<<grid, NT, 0, stream>>>(ds, dmin, dmax, off, sc, out);
}

// Round 3
// 271.579 us; speedup vs baseline: 1.0283x; 1.0283x over previous
//
#include <hip/hip_runtime.h>

// Problem constants (fixed by setup_inputs)
constexpr int Bc = 2, Dc = 48, Hc = 512, Wc = 640;
constexpr int HWc = Hc * Wc;

// Tile: 32x16 spatial, 256 threads, 2 consecutive-w pixels per thread.
// All 48 d-planes per block (DSPLIT=1) -> offset tensor fetched ONCE.
constexpr int TW = 32, TH = 16, NT = 256;
constexpr int NXT = Wc / TW;                  // 20 tiles in w
constexpr int NYT = Hc / TH;                  // 32 tiles in h
constexpr int NBLK = NXT * NYT * Bc;          // 1280 blocks
constexpr int NXCD = 8;
constexpr int BPX = NBLK / NXCD;              // 160 blocks per XCD
constexpr int HALO = 4;                       // far taps reach +/-4
constexpr int SW = TW + 2 * HALO;             // 40
constexpr int SH = TH + 2 * HALO;             // 24
constexpr int PLANE = SW * SH;                // 960 floats/plane
constexpr int DC = 2;                         // d-planes per barrier interval
constexpr int NIT = Dc / DC;                  // 24 intervals
constexpr int NVEC = DC * PLANE / 4;          // 480 float4 per interval
constexpr int VPT = (NVEC + NT - 1) / NT;     // 2
constexpr int NSC = DC * PLANE;               // 1920 scalars per interval
constexpr int SPT = (NSC + NT - 1) / NT;      // 8

__device__ __forceinline__ int reflect_h(int h) {
    return h < 0 ? -h : (h >= Hc ? 2 * (Hc - 1) - h : h);
}
__device__ __forceinline__ int reflect_w(int w) {
    return w < 0 ? -w : (w >= Wc ? 2 * (Wc - 1) - w : w);
}

// LDS = 15.36 KB; VGPR ~48. XCD-contiguous swizzle: hardware round-robins
// blockIdx%8 across XCDs, so logical = (hw%8)*160 + hw/8 gives each XCD a
// contiguous 20x8 tile band -> halo lines shared between neighbors hit the
// same 4MB L2 (per-interval live set ~1.2 MB/XCD).
__global__ __launch_bounds__(NT) void dw_kernel(
    const float* __restrict__ ds, const float* __restrict__ dmin,
    const float* __restrict__ dmax, const float* __restrict__ off,
    const float* __restrict__ scale_p, float* __restrict__ out)
{
    __shared__ float sx[2][DC * PLANE];       // double-buffered (15360 B)

    const int hw  = blockIdx.x;
    const int l   = (hw & (NXCD - 1)) * BPX + (hw >> 3);   // XCD-contiguous
    const int bx  = l % NXT;
    const int rem = l / NXT;
    const int by  = rem % NYT;
    const int b   = rem / NYT;
    const int h0  = by * TH;
    const int w0  = bx * TW;
    const int tid = threadIdx.x;
    const int col = tid & 15;                 // 16 float2-groups across 32 w
    const int row = tid >> 4;                 // 0..15

    const float inv_min   = 1.0f / dmin[b];
    const float inv_max   = 1.0f / dmax[b];
    const float invd      = 1.0f / (inv_min - inv_max);
    const float inv_scale = 1.0f / scale_p[0];

    // 18 offset channels x 2 pixels -> 36 registers (float2 loads), reused 48x.
    float offF[9][2], offN[9][2];
    {
        const float* op = off + (size_t)b * 18 * HWc
                        + (size_t)(h0 + row) * Wc + (w0 + 2 * col);
        #pragma unroll
        for (int s = 0; s < 9; ++s) {
            float2 vF = *(const float2*)(op + (size_t)s * HWc);
            float2 vN = *(const float2*)(op + (size_t)(s + 9) * HWc);
            offF[s][0] = vF.x; offF[s][1] = vF.y;
            offN[s][0] = vN.x; offN[s][1] = vN.y;
        }
    }

    const float* dsb  = ds  + (size_t)b * Dc * HWc;
    float*       outb = out + (size_t)b * Dc * HWc
                            + (size_t)(h0 + row) * Wc + (w0 + 2 * col);

    // Stencil for one interval. Per plane: 17 ds_read_b64 feed 2 pixels.
    auto compute = [&](const float* sb, int d0) {
        #pragma unroll
        for (int p = 0; p < DC; ++p) {
            // bp -> this thread's center pixel (even word offset: b64 aligned)
            const float* bp = sb + p * PLANE + (row + HALO) * SW + (HALO + 2 * col);
            float a0 = 0.f, a1 = 0.f, x00, x01;
            float2 t0, t1, t2, t3, t4;
            // dy=-4: far row sy=0 (taps at w-4, w, w+4)
            t0 = *(const float2*)(bp - 4 * SW - 4);
            t1 = *(const float2*)(bp - 4 * SW);
            t2 = *(const float2*)(bp - 4 * SW + 4);
            a0 += offF[0][0]*t0.x + offF[1][0]*t1.x + offF[2][0]*t2.x;
            a1 += offF[0][1]*t0.y + offF[1][1]*t1.y + offF[2][1]*t2.y;
            // dy=-2: near row sy=0 (taps at w-2, w, w+2)
            t0 = *(const float2*)(bp - 2 * SW - 2);
            t1 = *(const float2*)(bp - 2 * SW);
            t2 = *(const float2*)(bp - 2 * SW + 2);
            a0 += offN[0][0]*t0.x + offN[1][0]*t1.x + offN[2][0]*t2.x;
            a1 += offN[0][1]*t0.y + offN[1][1]*t1.y + offN[2][1]*t2.y;
            // dy=0: near+far sy=1, center
            t0 = *(const float2*)(bp - 4);
            t1 = *(const float2*)(bp - 2);
            t2 = *(const float2*)(bp);
            t3 = *(const float2*)(bp + 2);
            t4 = *(const float2*)(bp + 4);
            x00 = t2.x; x01 = t2.y;
            a0 += offN[3][0]*t1.x + offN[4][0]*t2.x + offN[5][0]*t3.x
                + offF[3][0]*t0.x + offF[4][0]*t2.x + offF[5][0]*t4.x;
            a1 += offN[3][1]*t1.y + offN[4][1]*t2.y + offN[5][1]*t3.y
                + offF[3][1]*t0.y + offF[4][1]*t2.y + offF[5][1]*t4.y;
            // dy=+2: near row sy=2
            t0 = *(const float2*)(bp + 2 * SW - 2);
            t1 = *(const float2*)(bp + 2 * SW);
            t2 = *(const float2*)(bp + 2 * SW + 2);
            a0 += offN[6][0]*t0.x + offN[7][0]*t1.x + offN[8][0]*t2.x;
            a1 += offN[6][1]*t0.y + offN[7][1]*t1.y + offN[8][1]*t2.y;
            // dy=+4: far row sy=2
            t0 = *(const float2*)(bp + 4 * SW - 4);
            t1 = *(const float2*)(bp + 4 * SW);
            t2 = *(const float2*)(bp + 4 * SW + 4);
            a0 += offF[6][0]*t0.x + offF[7][0]*t1.x + offF[8][0]*t2.x;
            a1 += offF[6][1]*t0.y + offF[7][1]*t1.y + offF[8][1]*t2.y;
            // epilogue
            float2 o;
            a0 *= 0.5f; a1 *= 0.5f;
            float x1a = fminf(fabsf(a0 - x00) * inv_scale, 4.0f);
            float x1b = fminf(fabsf(a1 - x01) * inv_scale, 4.0f);
            o.x = __builtin_amdgcn_rcpf(1.0f + __expf(-(4.0f - 2.0f * x1a)));
            o.y = __builtin_amdgcn_rcpf(1.0f + __expf(-(4.0f - 2.0f * x1b)));
            *(float2*)(outb + (size_t)(d0 + p) * HWc) = o;
        }
    };

    // w-reflect only touches first/last block column; others vectorize.
    const bool interior = (bx > 0) && (bx + 1 < NXT);

    if (interior) {
        int vsrc[VPT];                        // d-invariant source offsets
        #pragma unroll
        for (int i = 0; i < VPT; ++i) {
            int vid = tid + i * NT;
            if (vid < NVEC) {
                int p   = vid / (PLANE / 4);
                int rem2 = vid - p * (PLANE / 4);
                int r   = rem2 / (SW / 4);
                int j   = rem2 - r * (SW / 4);
                int hs  = reflect_h(h0 + r - HALO);
                vsrc[i] = p * HWc + hs * Wc + (w0 - HALO + 4 * j);
            } else vsrc[i] = 0;
        }
        float4 pre[VPT];
        auto issue = [&](int d0) {            // loads only -> in flight under compute
            const float* dp = dsb + (size_t)d0 * HWc;
            #pragma unroll
            for (int i = 0; i < VPT; ++i) {
                int vid = tid + i * NT;
                if (vid < NVEC) pre[i] = *(const float4*)(dp + vsrc[i]);
            }
        };
        auto commit = [&](float* sb) {
            #pragma unroll
            for (int i = 0; i < VPT; ++i) {
                int vid = tid + i * NT;
                if (vid < NVEC) {
                    float4 v = pre[i], x;
                    x.x = (__builtin_amdgcn_rcpf(v.x) - inv_max) * invd;
                    x.y = (__builtin_amdgcn_rcpf(v.y) - inv_max) * invd;
                    x.z = (__builtin_amdgcn_rcpf(v.z) - inv_max) * invd;
                    x.w = (__builtin_amdgcn_rcpf(v.w) - inv_max) * invd;
                    *(float4*)(sb + vid * 4) = x;
                }
            }
        };
        issue(0);
        commit(sx[0]);
        __syncthreads();
        for (int it = 0; it < NIT; ++it) {
            if (it + 1 < NIT) issue((it + 1) * DC);
            compute(sx[it & 1], it * DC);
            if (it + 1 < NIT) commit(sx[(it + 1) & 1]);
            __syncthreads();
        }
    } else {
        int ssrc[SPT];                        // scalar path (w-edge blocks)
        #pragma unroll
        for (int i = 0; i < SPT; ++i) {
            int idx = tid + i * NT;
            if (idx < NSC) {
                int p   = idx / PLANE;
                int rem2 = idx - p * PLANE;
                int r   = rem2 / SW;
                int c   = rem2 - r * SW;
                int hs  = reflect_h(h0 + r - HALO);
                int ws  = reflect_w(w0 + c - HALO);
                ssrc[i] = p * HWc + hs * Wc + ws;
            } else ssrc[i] = 0;
        }
        float pre[SPT];
        auto issue = [&](int d0) {
            const float* dp = dsb + (size_t)d0 * HWc;
            #pragma unroll
            for (int i = 0; i < SPT; ++i) {
                int idx = tid + i * NT;
                if (idx < NSC) pre[i] = dp[ssrc[i]];
            }
        };
        auto commit = [&](float* sb) {
            #pragma unroll
            for (int i = 0; i < SPT; ++i) {
                int idx = tid + i * NT;
                if (idx < NSC)
                    sb[idx] = (__builtin_amdgcn_rcpf(pre[i]) - inv_max) * invd;
            }
        };
        issue(0);
        commit(sx[0]);
        __syncthreads();
        for (int it = 0; it < NIT; ++it) {
            if (it + 1 < NIT) issue((it + 1) * DC);
            compute(sx[it & 1], it * DC);
            if (it + 1 < NIT) commit(sx[(it + 1) & 1]);
            __syncthreads();
        }
    }
}

extern "C" void kernel_launch(void* const* d_in, const int* in_sizes, int n_in,
                              void* d_out, int out_size, void* d_ws, size_t ws_size,
                              hipStream_t stream) {
    const float* ds   = (const float*)d_in[0];  // depth_sample [B,D,H,W]
    const float* dmin = (const float*)d_in[1];  // depth_min [B]
    const float* dmax = (const float*)d_in[2];  // depth_max [B]
    const float* off  = (const float*)d_in[3];  // offset [B,18,H,W]
    const float* sc   = (const float*)d_in[4];  // patchmatch_interval_scale
    float* out = (float*)d_out;                 // [B,D,H,W] fp32

    dim3 grid(NBLK, 1, 1);                      // flat; swizzled in-kernel
    dw_kernel<<<grid, NT, 0, stream>>>(ds, dmin, dmax, off, sc, out);
}